// Round 5
// baseline (313.716 us; speedup 1.0000x reference)
//
#include <hip/hip_runtime.h>

#define NN 100000
#define EE 400000
#define STRIPS 6250          // NN/16, exact
#define MARK_BLOCKS 391      // ceil((EE/4)/256)

typedef unsigned short u16;
typedef __attribute__((ext_vector_type(4))) float floatx4;
typedef __attribute__((ext_vector_type(8))) short shortx8;
typedef __attribute__((ext_vector_type(4))) unsigned short ushortx4;
typedef __attribute__((ext_vector_type(8))) unsigned short ushortx8;

__device__ __forceinline__ u16 f2bf(float f) {
    unsigned u = __float_as_uint(f);
    u += 0x7FFFu + ((u >> 16) & 1u);
    return (u16)(u >> 16);
}

// one atomic per wave, broadcast
__device__ __forceinline__ int qfetch(int* c, int lane) {
    int v = 0;
    if (lane == 0) v = atomicAdd(c, 1);
    return __shfl(v, 0);
}

// ---- fused pre-pass: zero queue counters + degree masks (idempotent byte
//      stores, int4 edge reads) + W -> bf16 MFMA-A-frag-order pre-pack
__global__ __launch_bounds__(256) void mark_conv(
    const int4* __restrict__ daa, const int4* __restrict__ dab,
    const int4* __restrict__ dba,
    const float* __restrict__ Wr0, const float* __restrict__ Wr1,
    unsigned char* __restrict__ m, u16* __restrict__ wbf,
    int* __restrict__ ctrs) {
    const int blk = blockIdx.x;
    if (blk == 0 && threadIdx.x < 2) ctrs[threadIdx.x * 64] = 0;  // 256B apart
    if (blk < MARK_BLOCKS) {
        int i = blk * 256 + threadIdx.x;
        if (i < EE / 4) {
            int4 a = daa[i], bb = dab[i], c = dba[i];
            m[a.x] = 1; m[a.y] = 1; m[a.z] = 1; m[a.w] = 1;
            m[NN + bb.x] = 1; m[NN + bb.y] = 1; m[NN + bb.z] = 1; m[NN + bb.w] = 1;
            m[2 * NN + c.x] = 1; m[2 * NN + c.y] = 1; m[2 * NN + c.z] = 1; m[2 * NN + c.w] = 1;
        }
    } else {
        // 32 blocks: 8192 threads, one ushortx8 (8 W values) each.
        // Layout matches fused2's af read: [type][mat][chunk 0..31][l2 0..63][j 0..7]
        int flat = (blk - MARK_BLOCKS) * 256 + threadIdx.x;  // [0, 8192)
        int type = flat >> 12;
        int mat = (flat >> 11) & 1;
        int chunk = (flat >> 6) & 31;
        int l2 = flat & 63;
        int kbase = (chunk >> 3) * 32 + (l2 >> 4) * 8;
        int n = (chunk & 7) * 16 + (l2 & 15);
        const float* W = (mat ? Wr1 : Wr0) + type * 16384;
        ushortx8 p;
#pragma unroll
        for (int j = 0; j < 8; ++j) p[j] = f2bf(W[(kbase + j) * 128 + n]);
        *(ushortx8*)&wbf[((type * 2 + mat) << 14) + chunk * 512 + l2 * 8] = p;
    }
}

// ---- persistent fused 2-layer, round-0 geometry restored + queue + bias-fold.
// out[m] = relu(s^2*(z@W1) + s*b1), z = relu(feat@W0 + b0)   [relu(s*x)=s*relu(x)]
// Transposed MFMA form D = W^T x feat^T (layouts HW-verified).
// 256 thr (4 waves), 80 KB LDS -> 2 blocks/CU, 8 waves/CU, direct 64B stores.
//
// GEOMETRY POST-MORTEM (rounds 1-4): 16-wave/128KB-LDS blocks inflated HBM
// traffic 155->370 MB REGARDLESS of store style (plain 64B, nt, staged
// full-line all ~370): per-XCD in-flight strip set (512 waves x ~24KB) is 3x
// the 4MB L2 -> feat/out round-trip through fabric; plus 3.05 strips/wave ->
// ceil 4 = 31% pigeonhole tail. Round-0 geometry keeps in-flight set ~L2-sized
// (WRITE == output size exactly) and 6.10 -> 7 = 15% tail.
// This round: (1) W pre-packed in mark_conv (startup = 64KB linear copy);
// (2) biases held in regs, b0 folded into MFMA acc-init (C-layout makes bias
// a per-lane constant) -> no per-strip bias loads/adds in the serial chain;
// (3) per-type atomic work queue fetched ONE STRIP AHEAD (atomic latency hides
// under a full iteration) -> absorbs straggler variance in the tail.
__global__ __launch_bounds__(256, 2) void fused2(
    const float* __restrict__ featA, const float* __restrict__ featB,
    const u16* __restrict__ wbf,
    const float* __restrict__ br0, const float* __restrict__ br1,
    const unsigned char* __restrict__ masks, int* __restrict__ ctrs,
    float* __restrict__ out) {
    __shared__ u16 lds[40960];   // 80 KB: [W0f 16384][W1f 16384][h1: 4 waves x 2048]

    const int type = blockIdx.x >> 8;           // 256 blocks per type
    const float* feat = type ? featB : featA;
    const float* b0 = br0 + type * 128;
    const float* b1 = br1 + type * 128;
    float* outp = out + (size_t)type * NN * 128;
    int* ctr = ctrs + type * 64;                // 256B apart per type

    const int t = threadIdx.x;
    const int wave = t >> 6, lane = t & 63;
    const int quad = lane >> 4, mrow = lane & 15;

    // ---- bias fragments, loaded ONCE (per-lane constants under C-layout)
    floatx4 b0f[8], b1f[8];
#pragma unroll
    for (int nt = 0; nt < 8; ++nt) {
        b0f[nt] = *(const floatx4*)(b0 + nt * 16 + quad * 4);
        b1f[nt] = *(const floatx4*)(b1 + nt * 16 + quad * 4);
    }

    // ---- initial queue fetches + strip-0 prefetch (before staging barrier)
    int s = qfetch(ctr, lane);                  // always < STRIPS (1024 waves/type)
    floatx4 pf[8];
    unsigned char pm0 = 0, pm1 = 0;
    {
        const float* arow = feat + (size_t)(s * 16 + mrow) * 128;
#pragma unroll
        for (int ks = 0; ks < 4; ++ks) {
            pf[2 * ks]     = *(const floatx4*)(arow + ks * 32 + quad * 8);
            pf[2 * ks + 1] = *(const floatx4*)(arow + ks * 32 + quad * 8 + 4);
        }
        int row = s * 16 + mrow;
        if (type) pm0 = masks[NN + row];
        else { pm0 = masks[row]; pm1 = masks[2 * NN + row]; }
    }
    int sn = qfetch(ctr, lane);                 // next strip, known a full iter ahead

    // ---- stage pre-packed W0f|W1f: 64 KB linear coalesced copy, 16 x 16B/thread
    {
        const ushortx8* __restrict__ wsrc = (const ushortx8*)(wbf + ((size_t)type << 15));
#pragma unroll
        for (int i = 0; i < 16; ++i) {
            int idx = i * 256 + t;              // [0, 4096) 16B chunks
            *(ushortx8*)&lds[idx * 8] = wsrc[idx];
        }
    }
    __syncthreads();   // the only barrier

    const int h1base = 32768 + wave * 2048;

    while (s < STRIPS) {
        // issue the atomic for the strip after next NOW (latency hidden)
        int snn = qfetch(ctr, lane);

        // consume prefetch: bf16 B-frags + scale (before overwriting pf)
        shortx8 bfrag[4];
#pragma unroll
        for (int ks = 0; ks < 4; ++ks) {
            floatx4 f0 = pf[2 * ks], f1 = pf[2 * ks + 1];
            union { shortx8 v; u16 u[8]; } uu;
            uu.u[0] = f2bf(f0[0]); uu.u[1] = f2bf(f0[1]);
            uu.u[2] = f2bf(f0[2]); uu.u[3] = f2bf(f0[3]);
            uu.u[4] = f2bf(f1[0]); uu.u[5] = f2bf(f1[1]);
            uu.u[6] = f2bf(f1[2]); uu.u[7] = f2bf(f1[3]);
            bfrag[ks] = uu.v;
        }
        const float scl = type ? (1.0f + (float)pm0) * 0.5f
                               : (1.0f + (float)pm0 + (float)pm1) * (1.0f / 3.0f);
        const float s2 = scl * scl;
        const int row = s * 16 + mrow;

        // prefetch next strip (hidden under both GEMMs)
        if (sn < STRIPS) {
            const float* arow = feat + (size_t)(sn * 16 + mrow) * 128;
#pragma unroll
            for (int ks = 0; ks < 4; ++ks) {
                pf[2 * ks]     = *(const floatx4*)(arow + ks * 32 + quad * 8);
                pf[2 * ks + 1] = *(const floatx4*)(arow + ks * 32 + quad * 8 + 4);
            }
            int nrow = sn * 16 + mrow;
            if (type) pm0 = masks[NN + nrow];
            else { pm0 = masks[nrow]; pm1 = masks[2 * NN + nrow]; }
        }

        // GEMM1: acc[nt] = W0^T tile(nt) x feat^T, acc init = b0 (bias for free)
        floatx4 acc[8];
#pragma unroll
        for (int nt = 0; nt < 8; ++nt) acc[nt] = b0f[nt];
#pragma unroll
        for (int ks = 0; ks < 4; ++ks)
#pragma unroll
            for (int nt = 0; nt < 8; ++nt) {
                shortx8 af = *(const shortx8*)&lds[((ks * 8 + nt) << 9) + lane * 8];
                acc[nt] = __builtin_amdgcn_mfma_f32_16x16x32_bf16(af, bfrag[ks], acc[nt], 0, 0, 0);
            }

        // epilogue1: z = relu(acc), wave-private h1 in GEMM2 B-frag order
#pragma unroll
        for (int nt = 0; nt < 8; ++nt) {
            ushortx4 p;
#pragma unroll
            for (int r = 0; r < 4; ++r)
                p[r] = f2bf(fmaxf(acc[nt][r], 0.0f));
            int q2 = (2 * nt + (quad >> 1)) & 3;
            *(ushortx4*)&lds[h1base + (nt >> 1) * 512 + q2 * 128 + mrow * 8 + (quad & 1) * 4] = p;
        }

        shortx8 h1b[4];
#pragma unroll
        for (int ks = 0; ks < 4; ++ks)
            h1b[ks] = *(const shortx8*)&lds[h1base + ks * 512 + lane * 8];

        // GEMM2: acc2[nt] = W1^T tile(nt) x z^T
        floatx4 acc2[8];
#pragma unroll
        for (int nt = 0; nt < 8; ++nt) acc2[nt] = (floatx4){0.f, 0.f, 0.f, 0.f};
#pragma unroll
        for (int ks = 0; ks < 4; ++ks)
#pragma unroll
            for (int nt = 0; nt < 8; ++nt) {
                shortx8 af = *(const shortx8*)&lds[16384 + ((ks * 8 + nt) << 9) + lane * 8];
                acc2[nt] = __builtin_amdgcn_mfma_f32_16x16x32_bf16(af, h1b[ks], acc2[nt], 0, 0, 0);
            }

        // epilogue2: out = relu(s^2*acc2 + s*b1), direct 64B stores
        // (round-0 geometry keeps WRITE == output size exactly)
        float* orow = outp + (size_t)row * 128;
#pragma unroll
        for (int nt = 0; nt < 8; ++nt) {
            floatx4 o;
#pragma unroll
            for (int r = 0; r < 4; ++r)
                o[r] = fmaxf(s2 * acc2[nt][r] + scl * b1f[nt][r], 0.0f);
            *(floatx4*)(orow + nt * 16 + quad * 4) = o;
        }

        s = sn; sn = snn;
    }
}

extern "C" void kernel_launch(void* const* d_in, const int* in_sizes, int n_in,
                              void* d_out, int out_size, void* d_ws, size_t ws_size,
                              hipStream_t stream) {
    (void)in_sizes; (void)n_in; (void)out_size; (void)ws_size;
    const float* featA = (const float*)d_in[0];
    const float* featB = (const float*)d_in[1];
    const int* dst_aa = (const int*)d_in[3];
    const int* dst_ab = (const int*)d_in[5];
    const int* dst_ba = (const int*)d_in[7];
    const float* Wr0 = (const float*)d_in[10];
    const float* br0 = (const float*)d_in[11];
    const float* Wr1 = (const float*)d_in[16];
    const float* br1 = (const float*)d_in[17];

    unsigned char* masks = (unsigned char*)d_ws;              // 3*NN bytes
    u16* wbf = (u16*)((char*)d_ws + (size_t)3 * NN);          // 131072 B (300000 % 16 == 0)
    int* ctrs = (int*)((char*)d_ws + (size_t)3 * NN + 131072); // 2 counters, 256B apart

    hipMemsetAsync(masks, 0, (size_t)3 * NN, stream);
    mark_conv<<<MARK_BLOCKS + 32, 256, 0, stream>>>(
        (const int4*)dst_aa, (const int4*)dst_ab, (const int4*)dst_ba,
        Wr0, Wr1, masks, wbf, ctrs);
    fused2<<<512, 256, 0, stream>>>(featA, featB, wbf, br0, br1,
                                    masks, ctrs, (float*)d_out);
}